// Round 4
// baseline (222.368 us; speedup 1.0000x reference)
//
#include <hip/hip_runtime.h>
#include <math.h>

#define FH 384
#define FW 384
#define DH 96
#define DW 96
#define NIMG 6   // 0,1: pred b0,b1; 2,3: I[:,0] b0,b1; 4,5: I[:,1] b0,b1
#define PLANE (DH * DW)
#define NPIX (2 * PLANE)

// Keys cubic kernel, a = -0.5 (matches jax.image "cubic")
__device__ __forceinline__ float keysc(float x) {
    if (x < 1.f) return ((1.5f * x - 2.5f) * x) * x + 1.f;
    if (x < 2.f) return ((-0.5f * x + 2.5f) * x - 4.f) * x + 2.f;
    return 0.f;
}

// reflect-101 (jnp.pad mode='reflect'), valid for i in [-(n-1), 2n-2]
__device__ __forceinline__ int refl(int i, int n) {
    if (i < 0) i = -i;
    if (i >= n) i = 2 * (n - 1) - i;
    return i;
}

// ---------------- K1: grayscale for 6 images -------------------------------
__global__ void k_gray(const float* __restrict__ pred, const float* __restrict__ I,
                       float* __restrict__ gray) {
    int idx = blockIdx.x * 256 + threadIdx.x;
    const int total = NIMG * FH * FW;
    if (idx >= total) return;
    int img = idx / (FH * FW);
    int px  = idx % (FH * FW);
    const float* src;
    if (img < 2) {
        src = pred + img * 3 * FH * FW;
    } else {
        int j = (img - 2) >> 1, b = (img - 2) & 1;
        src = I + ((b * 2 + j) * 3) * FH * FW;
    }
    float r = src[px], g = src[FH * FW + px], b = src[2 * FH * FW + px];
    gray[idx] = (0.299f * r + 0.587f * g + 0.114f * b) * 255.0f;
}

// ---------------- K2: census + downsample along H --------------------------
// out CH[img][k][yo][x], k in 0..8 (census channel), x full-res col
__global__ void k_census_downH(const float* __restrict__ gray, float* __restrict__ CH) {
    int idx = blockIdx.x * 256 + threadIdx.x;
    const int total = NIMG * 9 * DH * FW;
    if (idx >= total) return;
    int x  = idx % FW;
    int t1 = idx / FW;
    int yo = t1 % DH;
    int t2 = t1 / DH;
    int k  = t2 % 9;
    int img = t2 / 9;
    int dy = k / 3 - 1, dx = k % 3 - 1;
    const float* g = gray + img * FH * FW;
    float acc = 0.f, z = 0.f;
#pragma unroll
    for (int t = 0; t < 16; ++t) {
        int r = 4 * yo - 6 + t;
        if (r < 0 || r >= FH) continue;
        float w = keysc(fabsf((float)t - 7.5f) * 0.25f);
        z += w;
        float gc = g[r * FW + x];
        int r2 = r + dy, c2 = x + dx;
        float gn = (r2 < 0 || r2 >= FH || c2 < 0 || c2 >= FW) ? 0.f : g[r2 * FW + c2];
        float tt = gn - gc;
        acc += w * (tt / sqrtf(0.81f + tt * tt));
    }
    CH[idx] = acc / z;
}

// ---------------- K3: generic downsample along W ---------------------------
// src: [nrows][FW] -> dst: [nrows][DW]  (CH|RH -> CD|RD, laid out contiguously)
__global__ void k_downW(const float* __restrict__ src, float* __restrict__ dst, int nrows) {
    int idx = blockIdx.x * 256 + threadIdx.x;
    int total = nrows * DW;
    if (idx >= total) return;
    int xo = idx % DW;
    int row = idx / DW;
    const float* s = src + row * FW;
    float acc = 0.f, z = 0.f;
#pragma unroll
    for (int t = 0; t < 16; ++t) {
        int i = 4 * xo - 6 + t;
        if (i < 0 || i >= FW) continue;
        float w = keysc(fabsf((float)t - 7.5f) * 0.25f);
        z += w;
        acc += w * s[i];
    }
    dst[idx] = acc / z;
}

// ---------------- K4: raw channels downsample along H ----------------------
// out RH[img][c][yo][x]
__global__ void k_raw_downH(const float* __restrict__ pred, const float* __restrict__ I,
                            float* __restrict__ RH) {
    int idx = blockIdx.x * 256 + threadIdx.x;
    const int total = NIMG * 3 * DH * FW;
    if (idx >= total) return;
    int x  = idx % FW;
    int t1 = idx / FW;
    int yo = t1 % DH;
    int t2 = t1 / DH;
    int c  = t2 % 3;
    int img = t2 / 3;
    const float* src;
    if (img < 2) {
        src = pred + (img * 3 + c) * FH * FW;
    } else {
        int j = (img - 2) >> 1, b = (img - 2) & 1;
        src = I + (((b * 2 + j) * 3) + c) * FH * FW;
    }
    float acc = 0.f, z = 0.f;
#pragma unroll
    for (int t = 0; t < 16; ++t) {
        int r = 4 * yo - 6 + t;
        if (r < 0 || r >= FH) continue;
        float w = keysc(fabsf((float)t - 7.5f) * 0.25f);
        z += w;
        acc += w * src[r * FW + x];
    }
    RH[idx] = acc / z;
}

// ---------------- K5: n2 per (neighbor image, position) --------------------
// N2[img4][pos], img4 = 2j+b -> CD image 2+img4; f-order sequential sum
__global__ void k_n2(const float* __restrict__ CD, float* __restrict__ N2) {
    int idx = blockIdx.x * 256 + threadIdx.x;
    if (idx >= 4 * PLANE) return;
    int img4 = idx / PLANE;
    int pos  = idx % PLANE;
    int y = pos / DW, x = pos % DW;
    int ry[3], rx[3];
#pragma unroll
    for (int kk = 0; kk < 3; ++kk) {
        ry[kk] = refl(y + kk - 1, DH);
        rx[kk] = refl(x + kk - 1, DW);
    }
    const float* C = CD + (2 + img4) * 9 * PLANE;
    float s = 0.f;
#pragma unroll
    for (int c = 0; c < 9; ++c)
#pragma unroll
        for (int ky = 0; ky < 3; ++ky)
#pragma unroll
            for (int kx = 0; kx < 3; ++kx) {
                float v = C[c * PLANE + ry[ky] * DW + rx[kx]];
                s += v * v;
            }
    N2[idx] = s;
}

// ---------------- K6: matching, pixel-coalesced, candidate-grouped ---------
// thread = (pixel, group g); candidates n = 8k+g; lanes = consecutive pixels
__global__ __launch_bounds__(256) void k_match(const float* __restrict__ CD,
                                               const float* __restrict__ N2,
                                               float* __restrict__ bestd,
                                               int* __restrict__ bestn) {
    int g    = blockIdx.x & 7;
    int tile = blockIdx.x >> 3;            // 0..71
    int pid  = tile * 256 + threadIdx.x;   // 0..18431
    int b   = pid / PLANE;
    int pos = pid % PLANE;
    int y = pos / DW, x = pos % DW;

    const float* CDb = CD + b * 9 * PLANE;
    int ry0[3], rx0[3];
#pragma unroll
    for (int kk = 0; kk < 3; ++kk) {
        ry0[kk] = refl(y + kk - 1, DH);
        rx0[kk] = refl(x + kk - 1, DW);
    }

    // center census patch in registers (static indexing only)
    float p[81];
#pragma unroll
    for (int c = 0; c < 9; ++c)
#pragma unroll
        for (int ky = 0; ky < 3; ++ky)
#pragma unroll
            for (int kx = 0; kx < 3; ++kx)
                p[c * 9 + ky * 3 + kx] = CDb[c * PLANE + ry0[ky] * DW + rx0[kx]];

    float best = INFINITY;
    int bn = 1 << 30;
    for (int k = 0; k < 13; ++k) {
        int n = 8 * k + g;
        if (n >= 98) break;
        int j = n / 49, rr = n % 49;
        int dy = rr / 7 - 3, dx = rr % 7 - 3;
        int yy = refl(y + dy, DH), xx = refl(x + dx, DW);   // first reflect
        const float* CDn = CD + (2 + 2 * j + b) * 9 * PLANE;
        int ry[3], rx[3];
#pragma unroll
        for (int kk = 0; kk < 3; ++kk) {                    // second reflect
            ry[kk] = refl(yy + kk - 1, DH);
            rx[kk] = refl(xx + kk - 1, DW);
        }
        float dot = 0.f;
#pragma unroll
        for (int c = 0; c < 9; ++c)
#pragma unroll
            for (int ky = 0; ky < 3; ++ky)
#pragma unroll
                for (int kx = 0; kx < 3; ++kx)
                    dot += p[c * 9 + ky * 3 + kx] * CDn[c * PLANE + ry[ky] * DW + rx[kx]];
        float dis = N2[(2 * j + b) * PLANE + yy * DW + xx] - 2.f * dot;
        if (dis < best) { best = dis; bn = n; }   // n ascending in k => first occurrence
    }
    bestd[g * NPIX + pid] = best;
    bestn[g * NPIX + pid] = bn;
}

// ---------------- K7: combine groups + loss gather -------------------------
__global__ __launch_bounds__(256) void k_combine(const float* __restrict__ bestd,
                                                 const int* __restrict__ bestn,
                                                 const float* __restrict__ RD,
                                                 float* __restrict__ partial) {
    int pid = blockIdx.x * 256 + threadIdx.x;   // 0..18431
    int b   = pid / PLANE;
    int pos = pid % PLANE;
    int y = pos / DW, x = pos % DW;

    float best = INFINITY;
    int bn = 1 << 30;
#pragma unroll
    for (int g = 0; g < 8; ++g) {
        float d = bestd[g * NPIX + pid];
        int   n = bestn[g * NPIX + pid];
        if (d < best || (d == best && n < bn)) { best = d; bn = n; }
    }

    int ry0[3], rx0[3];
#pragma unroll
    for (int kk = 0; kk < 3; ++kk) {
        ry0[kk] = refl(y + kk - 1, DH);
        rx0[kk] = refl(x + kk - 1, DW);
    }
    int j = bn / 49, rr = bn % 49;
    int dy = rr / 7 - 3, dx = rr % 7 - 3;
    int yy = refl(y + dy, DH), xx = refl(x + dx, DW);
    int ry[3], rx[3];
#pragma unroll
    for (int kk = 0; kk < 3; ++kk) {
        ry[kk] = refl(yy + kk - 1, DH);
        rx[kk] = refl(xx + kk - 1, DW);
    }
    const float* RDp = RD + b * 3 * PLANE;
    const float* RDn = RD + (2 + 2 * j + b) * 3 * PLANE;
    float loss = 0.f;
#pragma unroll
    for (int c = 0; c < 3; ++c)
#pragma unroll
        for (int ky = 0; ky < 3; ++ky)
#pragma unroll
            for (int kx = 0; kx < 3; ++kx) {
                float a = RDp[c * PLANE + ry0[ky] * DW + rx0[kx]];
                float m = RDn[c * PLANE + ry[ky] * DW + rx[kx]];
                float d = a - m;
                loss += d * d;
            }

    __shared__ float red[256];
    red[threadIdx.x] = loss;
    __syncthreads();
#pragma unroll
    for (int s = 128; s > 0; s >>= 1) {
        if (threadIdx.x < s) red[threadIdx.x] += red[threadIdx.x + s];
        __syncthreads();
    }
    if (threadIdx.x == 0) partial[blockIdx.x] = red[0];
}

// ---------------- K8: final reduction --------------------------------------
#define NPART 72
__global__ void k_final(const float* __restrict__ partial, float* __restrict__ out) {
    __shared__ float red[128];
    float v = (threadIdx.x < NPART) ? partial[threadIdx.x] : 0.f;
    red[threadIdx.x] = v;
    __syncthreads();
#pragma unroll
    for (int s = 64; s > 0; s >>= 1) {
        if (threadIdx.x < s) red[threadIdx.x] += red[threadIdx.x + s];
        __syncthreads();
    }
    // mean over [b=2, hw=9216, 27] with the 0.5 factor
    if (threadIdx.x == 0) out[0] = red[0] * (0.5f / 497664.0f);
}

extern "C" void kernel_launch(void* const* d_in, const int* in_sizes, int n_in,
                              void* d_out, int out_size, void* d_ws, size_t ws_size,
                              hipStream_t stream) {
    const float* pred = (const float*)d_in[0];   // [2,3,384,384]
    const float* I    = (const float*)d_in[1];   // [2,2,3,384,384]
    float* out = (float*)d_out;
    float* ws  = (float*)d_ws;

    // workspace layout (floats):
    //   CD   [0, 497664)                       6*9*96*96
    //   RD   [497664, 663552)                  6*3*96*96
    //   scratch S = 663552 (3538944 floats, same footprint as prior rounds):
    //     gray [S, S+884736)                   6*384*384   (dead after census_downH)
    //     CH   [S+884736, S+2875392)           6*9*96*384  (dead after downW)
    //     RH   [S+2875392, S+3538944)          6*3*96*384  (dead after downW)
    //   After downW, gray region is re-used:
    //     N2    [S, S+36864)                   4*9216
    //     bestd [S+36864, S+184320)            8*18432
    //     bestn [S+184320, S+331776)           8*18432 (int)
    //     part  [S+331776, S+331848)           72
    float* CD   = ws;
    float* RD   = CD + 497664;
    float* S    = RD + 165888;
    float* gray = S;
    float* CH   = S + 884736;
    float* RH   = CH + 1990656;
    float* N2   = S;
    float* bestd = S + 36864;
    int*   bestn = (int*)(S + 184320);
    float* part  = S + 331776;

    k_gray<<<(NIMG * FH * FW + 255) / 256, 256, 0, stream>>>(pred, I, gray);
    k_census_downH<<<(NIMG * 9 * DH * FW + 255) / 256, 256, 0, stream>>>(gray, CH);
    k_raw_downH<<<(NIMG * 3 * DH * FW + 255) / 256, 256, 0, stream>>>(pred, I, RH);
    // one combined W-downsample over CH|RH rows -> CD|RD
    k_downW<<<((NIMG * 12 * DH) * DW + 255) / 256, 256, 0, stream>>>(CH, CD, NIMG * 12 * DH);
    k_n2<<<(4 * PLANE + 255) / 256, 256, 0, stream>>>(CD, N2);
    k_match<<<72 * 8, 256, 0, stream>>>(CD, N2, bestd, bestn);
    k_combine<<<NPIX / 256, 256, 0, stream>>>(bestd, bestn, RD, part);
    k_final<<<1, 128, 0, stream>>>(part, out);
}

// Round 5
// 141.286 us; speedup vs baseline: 1.5739x; 1.5739x over previous
//
#include <hip/hip_runtime.h>
#include <math.h>

#define FH 384
#define FW 384
#define DH 96
#define DW 96
#define NIMG 6   // 0,1: pred b0,b1; 2,3: I[:,0] b0,b1; 4,5: I[:,1] b0,b1
#define PLANE (DH * DW)
#define NPIX (2 * PLANE)

// Keys cubic kernel, a = -0.5 (matches jax.image "cubic")
__device__ __forceinline__ float keysc(float x) {
    if (x < 1.f) return ((1.5f * x - 2.5f) * x) * x + 1.f;
    if (x < 2.f) return ((-0.5f * x + 2.5f) * x - 4.f) * x + 2.f;
    return 0.f;
}

// reflect-101 (jnp.pad mode='reflect'), valid for i in [-(n-1), 2n-2]
__device__ __forceinline__ int refl(int i, int n) {
    if (i < 0) i = -i;
    if (i >= n) i = 2 * (n - 1) - i;
    return i;
}

__device__ __forceinline__ int clampi(int i) { return min(max(i, 0), 95); }

// ---------------- K1: grayscale for 6 images -------------------------------
__global__ void k_gray(const float* __restrict__ pred, const float* __restrict__ I,
                       float* __restrict__ gray) {
    int idx = blockIdx.x * 256 + threadIdx.x;
    const int total = NIMG * FH * FW;
    if (idx >= total) return;
    int img = idx / (FH * FW);
    int px  = idx % (FH * FW);
    const float* src;
    if (img < 2) {
        src = pred + img * 3 * FH * FW;
    } else {
        int j = (img - 2) >> 1, b = (img - 2) & 1;
        src = I + ((b * 2 + j) * 3) * FH * FW;
    }
    float r = src[px], g = src[FH * FW + px], b = src[2 * FH * FW + px];
    gray[idx] = (0.299f * r + 0.587f * g + 0.114f * b) * 255.0f;
}

// ---------------- K2: census + downsample along H --------------------------
__global__ void k_census_downH(const float* __restrict__ gray, float* __restrict__ CH) {
    int idx = blockIdx.x * 256 + threadIdx.x;
    const int total = NIMG * 9 * DH * FW;
    if (idx >= total) return;
    int x  = idx % FW;
    int t1 = idx / FW;
    int yo = t1 % DH;
    int t2 = t1 / DH;
    int k  = t2 % 9;
    int img = t2 / 9;
    int dy = k / 3 - 1, dx = k % 3 - 1;
    const float* g = gray + img * FH * FW;
    float acc = 0.f, z = 0.f;
#pragma unroll
    for (int t = 0; t < 16; ++t) {
        int r = 4 * yo - 6 + t;
        if (r < 0 || r >= FH) continue;
        float w = keysc(fabsf((float)t - 7.5f) * 0.25f);
        z += w;
        float gc = g[r * FW + x];
        int r2 = r + dy, c2 = x + dx;
        float gn = (r2 < 0 || r2 >= FH || c2 < 0 || c2 >= FW) ? 0.f : g[r2 * FW + c2];
        float tt = gn - gc;
        acc += w * (tt / sqrtf(0.81f + tt * tt));
    }
    CH[idx] = acc / z;
}

// ---------------- K3: generic downsample along W ---------------------------
__global__ void k_downW(const float* __restrict__ src, float* __restrict__ dst, int nrows) {
    int idx = blockIdx.x * 256 + threadIdx.x;
    int total = nrows * DW;
    if (idx >= total) return;
    int xo = idx % DW;
    int row = idx / DW;
    const float* s = src + row * FW;
    float acc = 0.f, z = 0.f;
#pragma unroll
    for (int t = 0; t < 16; ++t) {
        int i = 4 * xo - 6 + t;
        if (i < 0 || i >= FW) continue;
        float w = keysc(fabsf((float)t - 7.5f) * 0.25f);
        z += w;
        acc += w * s[i];
    }
    dst[idx] = acc / z;
}

// ---------------- K4: raw channels downsample along H ----------------------
__global__ void k_raw_downH(const float* __restrict__ pred, const float* __restrict__ I,
                            float* __restrict__ RH) {
    int idx = blockIdx.x * 256 + threadIdx.x;
    const int total = NIMG * 3 * DH * FW;
    if (idx >= total) return;
    int x  = idx % FW;
    int t1 = idx / FW;
    int yo = t1 % DH;
    int t2 = t1 / DH;
    int c  = t2 % 3;
    int img = t2 / 3;
    const float* src;
    if (img < 2) {
        src = pred + (img * 3 + c) * FH * FW;
    } else {
        int j = (img - 2) >> 1, b = (img - 2) & 1;
        src = I + (((b * 2 + j) * 3) + c) * FH * FW;
    }
    float acc = 0.f, z = 0.f;
#pragma unroll
    for (int t = 0; t < 16; ++t) {
        int r = 4 * yo - 6 + t;
        if (r < 0 || r >= FH) continue;
        float w = keysc(fabsf((float)t - 7.5f) * 0.25f);
        z += w;
        acc += w * src[r * FW + x];
    }
    RH[idx] = acc / z;
}

// ---------------- K5: n2 per (neighbor image, position) --------------------
__global__ void k_n2(const float* __restrict__ CD, float* __restrict__ N2) {
    int idx = blockIdx.x * 256 + threadIdx.x;
    if (idx >= 4 * PLANE) return;
    int img4 = idx / PLANE;
    int pos  = idx % PLANE;
    int y = pos / DW, x = pos % DW;
    int ry[3], rx[3];
#pragma unroll
    for (int kk = 0; kk < 3; ++kk) {
        ry[kk] = refl(y + kk - 1, DH);
        rx[kk] = refl(x + kk - 1, DW);
    }
    const float* C = CD + (2 + img4) * 9 * PLANE;
    float s = 0.f;
#pragma unroll
    for (int c = 0; c < 9; ++c)
#pragma unroll
        for (int ky = 0; ky < 3; ++ky)
#pragma unroll
            for (int kx = 0; kx < 3; ++kx) {
                float v = C[c * PLANE + ry[ky] * DW + rx[kx]];
                s += v * v;
            }
    N2[idx] = s;
}

// ---------------- K6: matching via LDS-staged windows ----------------------
// block = 32 px of one row (y) x 8 candidate groups; grid = 2b * 96 rows * 3 xtiles
__global__ __launch_bounds__(256) void k_match(const float* __restrict__ CD,
                                               const float* __restrict__ N2,
                                               const float* __restrict__ RD,
                                               float* __restrict__ partial) {
    __shared__ float nb[2][9][9][40];   // [j][c][row y-4+u][col x0-4+v]
    __shared__ float ct[9][3][34];      // [c][row y-1+u][col x0-1+v]
    __shared__ float sbd[256];
    __shared__ int   sbn[256];
    __shared__ float red[32];

    int bid = blockIdx.x;          // b*288 + y*3 + xt
    int b   = bid / 288;
    int rem = bid % 288;
    int y   = rem / 3;
    int x0  = (rem % 3) * 32;

    int px = threadIdx.x & 31;
    int g  = threadIdx.x >> 5;     // candidate group 0..7
    int x  = x0 + px;

    // ---- stage neighbor windows (clamped absolute coords; unused slots never read)
    for (int idx = threadIdx.x; idx < 2 * 9 * 9 * 40; idx += 256) {
        int j   = idx / 3240;
        int r1  = idx % 3240;
        int c   = r1 / 360;
        int r2  = r1 % 360;
        int u   = r2 / 40;
        int v   = r2 % 40;
        int gy  = clampi(y - 4 + u);
        int gx  = clampi(x0 - 4 + v);
        nb[j][c][u][v] = CD[((2 + 2 * j + b) * 9 + c) * PLANE + gy * DW + gx];
    }
    // ---- stage center window
    for (int idx = threadIdx.x; idx < 9 * 3 * 34; idx += 256) {
        int c = idx / 102;
        int r1 = idx % 102;
        int u = r1 / 34;
        int v = r1 % 34;
        int gy = clampi(y - 1 + u);
        int gx = clampi(x0 - 1 + v);
        ct[c][u][v] = CD[(b * 9 + c) * PLANE + gy * DW + gx];
    }
    __syncthreads();

    // center patch slots (relative to staged windows)
    int cy_s[3], cx_s[3];
#pragma unroll
    for (int kk = 0; kk < 3; ++kk) {
        cy_s[kk] = refl(y + kk - 1, DH) - (y - 1);
        cx_s[kk] = refl(x + kk - 1, DW) - (x0 - 1);
    }

    float best = INFINITY;
    int bn = 1 << 30;
    for (int k = 0; k < 13; ++k) {
        int n = 8 * k + g;
        if (n >= 98) break;
        int j = n / 49, rr = n % 49;
        int dy = rr / 7 - 3, dx = rr % 7 - 3;
        int yy = refl(y + dy, DH), xx = refl(x + dx, DW);   // first reflect
        int ry_s[3], rx_s[3];
#pragma unroll
        for (int kk = 0; kk < 3; ++kk) {                    // second reflect -> slots
            ry_s[kk] = refl(yy + kk - 1, DH) - (y - 4);
            rx_s[kk] = refl(xx + kk - 1, DW) - (x0 - 4);
        }
        float dot = 0.f;
#pragma unroll
        for (int c = 0; c < 9; ++c)
#pragma unroll
            for (int ky = 0; ky < 3; ++ky)
#pragma unroll
                for (int kx = 0; kx < 3; ++kx)
                    dot += ct[c][cy_s[ky]][cx_s[kx]] * nb[j][c][ry_s[ky]][rx_s[kx]];
        float dis = N2[(2 * j + b) * PLANE + yy * DW + xx] - 2.f * dot;
        if (dis < best) { best = dis; bn = n; }   // n ascending within group
    }
    sbd[threadIdx.x] = best;
    sbn[threadIdx.x] = bn;
    __syncthreads();

    // ---- per-pixel lex-min across the 8 groups + loss gather (g==0 threads)
    float loss = 0.f;
    if (g == 0) {
        float d0 = sbd[px];
        int   n0 = sbn[px];
#pragma unroll
        for (int gg = 1; gg < 8; ++gg) {
            float d = sbd[gg * 32 + px];
            int   n = sbn[gg * 32 + px];
            if (d < d0 || (d == d0 && n < n0)) { d0 = d; n0 = n; }
        }
        int j = n0 / 49, rr = n0 % 49;
        int dy = rr / 7 - 3, dx = rr % 7 - 3;
        int yy = refl(y + dy, DH), xx = refl(x + dx, DW);
        int ry0[3], rx0[3], ry[3], rx[3];
#pragma unroll
        for (int kk = 0; kk < 3; ++kk) {
            ry0[kk] = refl(y + kk - 1, DH);
            rx0[kk] = refl(x + kk - 1, DW);
            ry[kk]  = refl(yy + kk - 1, DH);
            rx[kk]  = refl(xx + kk - 1, DW);
        }
        const float* RDp = RD + b * 3 * PLANE;
        const float* RDn = RD + (2 + 2 * j + b) * 3 * PLANE;
#pragma unroll
        for (int c = 0; c < 3; ++c)
#pragma unroll
            for (int ky = 0; ky < 3; ++ky)
#pragma unroll
                for (int kx = 0; kx < 3; ++kx) {
                    float a = RDp[c * PLANE + ry0[ky] * DW + rx0[kx]];
                    float m = RDn[c * PLANE + ry[ky] * DW + rx[kx]];
                    float d = a - m;
                    loss += d * d;
                }
        red[px] = loss;
    }
    __syncthreads();
    if (threadIdx.x == 0) {
        float s = 0.f;
#pragma unroll
        for (int i = 0; i < 32; ++i) s += red[i];
        partial[bid] = s;
    }
}

// ---------------- K8: final reduction --------------------------------------
#define NPART 576
__global__ void k_final(const float* __restrict__ partial, float* __restrict__ out) {
    __shared__ float red[256];
    float v = 0.f;
    for (int i = threadIdx.x; i < NPART; i += 256) v += partial[i];
    red[threadIdx.x] = v;
    __syncthreads();
#pragma unroll
    for (int s = 128; s > 0; s >>= 1) {
        if (threadIdx.x < s) red[threadIdx.x] += red[threadIdx.x + s];
        __syncthreads();
    }
    // mean over [b=2, hw=9216, 27] with the 0.5 factor
    if (threadIdx.x == 0) out[0] = red[0] * (0.5f / 497664.0f);
}

extern "C" void kernel_launch(void* const* d_in, const int* in_sizes, int n_in,
                              void* d_out, int out_size, void* d_ws, size_t ws_size,
                              hipStream_t stream) {
    const float* pred = (const float*)d_in[0];   // [2,3,384,384]
    const float* I    = (const float*)d_in[1];   // [2,2,3,384,384]
    float* out = (float*)d_out;
    float* ws  = (float*)d_ws;

    // workspace layout (floats):
    //   CD   [0, 497664)                       6*9*96*96
    //   RD   [497664, 663552)                  6*3*96*96
    //   scratch S = 663552:
    //     gray [S, S+884736)       (dead after census_downH)
    //     CH   [S+884736, S+2875392)  (dead after downW)
    //     RH   [S+2875392, S+3538944) (dead after downW)
    //   reused after downW:
    //     N2   [S, S+36864)
    //     part [S+36864, S+37440)             576
    float* CD   = ws;
    float* RD   = CD + 497664;
    float* S    = RD + 165888;
    float* gray = S;
    float* CH   = S + 884736;
    float* RH   = CH + 1990656;
    float* N2   = S;
    float* part = S + 36864;

    k_gray<<<(NIMG * FH * FW + 255) / 256, 256, 0, stream>>>(pred, I, gray);
    k_census_downH<<<(NIMG * 9 * DH * FW + 255) / 256, 256, 0, stream>>>(gray, CH);
    k_raw_downH<<<(NIMG * 3 * DH * FW + 255) / 256, 256, 0, stream>>>(pred, I, RH);
    k_downW<<<((NIMG * 12 * DH) * DW + 255) / 256, 256, 0, stream>>>(CH, CD, NIMG * 12 * DH);
    k_n2<<<(4 * PLANE + 255) / 256, 256, 0, stream>>>(CD, N2);
    k_match<<<576, 256, 0, stream>>>(CD, N2, RD, part);
    k_final<<<1, 256, 0, stream>>>(part, out);
}

// Round 6
// 134.659 us; speedup vs baseline: 1.6513x; 1.0492x over previous
//
#include <hip/hip_runtime.h>
#include <math.h>

#define FH 384
#define FW 384
#define DH 96
#define DW 96
#define NIMG 6   // 0,1: pred b0,b1; 2,3: I[:,0] b0,b1; 4,5: I[:,1] b0,b1
#define PLANE (DH * DW)
#define NPIX (2 * PLANE)

// Keys cubic kernel, a = -0.5 (matches jax.image "cubic")
__device__ __forceinline__ float keysc(float x) {
    if (x < 1.f) return ((1.5f * x - 2.5f) * x) * x + 1.f;
    if (x < 2.f) return ((-0.5f * x + 2.5f) * x - 4.f) * x + 2.f;
    return 0.f;
}

// reflect-101 (jnp.pad mode='reflect'), valid for i in [-(n-1), 2n-2]
__device__ __forceinline__ int refl(int i, int n) {
    if (i < 0) i = -i;
    if (i >= n) i = 2 * (n - 1) - i;
    return i;
}

__device__ __forceinline__ int clampi(int i) { return min(max(i, 0), 95); }

// soft census normalize — EXACT expression the reference lowers to (keep!)
__device__ __forceinline__ float softsign(float t) {
    return t / sqrtf(0.81f + t * t);
}

// ---------------- K1: grayscale for 6 images -------------------------------
__global__ void k_gray(const float* __restrict__ pred, const float* __restrict__ I,
                       float* __restrict__ gray) {
    int idx = blockIdx.x * 256 + threadIdx.x;
    const int total = NIMG * FH * FW;
    if (idx >= total) return;
    int img = idx / (FH * FW);
    int px  = idx % (FH * FW);
    const float* src;
    if (img < 2) {
        src = pred + img * 3 * FH * FW;
    } else {
        int j = (img - 2) >> 1, b = (img - 2) & 1;
        src = I + ((b * 2 + j) * 3) * FH * FW;
    }
    float r = src[px], g = src[FH * FW + px], b = src[2 * FH * FW + px];
    gray[idx] = (0.299f * r + 0.587f * g + 0.114f * b) * 255.0f;
}

// ---------------- K2: census (all 9 channels) + downsample along H ---------
// thread = (img, yo, x); sliding 3-row window; out CH[img][k][yo][x]
__global__ __launch_bounds__(256) void k_census_downH(const float* __restrict__ gray,
                                                      float* __restrict__ CH) {
    int idx = blockIdx.x * 256 + threadIdx.x;
    const int total = NIMG * DH * FW;
    if (idx >= total) return;
    int x   = idx % FW;
    int t1  = idx / FW;
    int yo  = t1 % DH;
    int img = t1 / DH;
    const float* g = gray + img * FH * FW;

    bool xl = (x > 0), xr = (x < FW - 1);

    float a0, a1, a2, b0, b1, b2, c0, c1, c2;   // rows r-1, r, r+1 at x-1,x,x+1
    auto loadrow = [&](int r, float& v0, float& v1, float& v2) {
        if (r < 0 || r >= FH) { v0 = v1 = v2 = 0.f; return; }
        const float* gr = g + r * FW + x;
        v1 = gr[0];
        v0 = xl ? gr[-1] : 0.f;
        v2 = xr ? gr[1] : 0.f;
    };

    int rbase = 4 * yo - 6;
    loadrow(rbase - 1, a0, a1, a2);
    loadrow(rbase,     b0, b1, b2);

    float acc0 = 0.f, acc1 = 0.f, acc2 = 0.f, acc3 = 0.f, acc5 = 0.f,
          acc6 = 0.f, acc7 = 0.f, acc8 = 0.f, z = 0.f;
#pragma unroll
    for (int t = 0; t < 16; ++t) {
        int r = rbase + t;
        loadrow(r + 1, c0, c1, c2);
        if (r >= 0 && r < FH) {
            float w = keysc(fabsf((float)t - 7.5f) * 0.25f);
            z += w;
            float gc = b1;
            acc0 += w * softsign(a0 - gc);
            acc1 += w * softsign(a1 - gc);
            acc2 += w * softsign(a2 - gc);
            acc3 += w * softsign(b0 - gc);
            acc5 += w * softsign(b2 - gc);
            acc6 += w * softsign(c0 - gc);
            acc7 += w * softsign(c1 - gc);
            acc8 += w * softsign(c2 - gc);
        }
        a0 = b0; a1 = b1; a2 = b2;
        b0 = c0; b1 = c1; b2 = c2;
    }
    float inv = 1.f / z;
    float* o = CH + (img * 9 * DH + yo) * FW + x;
    const int STR = DH * FW;
    o[0 * STR] = acc0 * inv;
    o[1 * STR] = acc1 * inv;
    o[2 * STR] = acc2 * inv;
    o[3 * STR] = acc3 * inv;
    o[4 * STR] = 0.f;                 // center channel: t - gray == 0 exactly
    o[5 * STR] = acc5 * inv;
    o[6 * STR] = acc6 * inv;
    o[7 * STR] = acc7 * inv;
    o[8 * STR] = acc8 * inv;
}

// ---------------- K3: generic downsample along W ---------------------------
__global__ void k_downW(const float* __restrict__ src, float* __restrict__ dst, int nrows) {
    int idx = blockIdx.x * 256 + threadIdx.x;
    int total = nrows * DW;
    if (idx >= total) return;
    int xo = idx % DW;
    int row = idx / DW;
    const float* s = src + row * FW;
    float acc = 0.f, z = 0.f;
#pragma unroll
    for (int t = 0; t < 16; ++t) {
        int i = 4 * xo - 6 + t;
        if (i < 0 || i >= FW) continue;
        float w = keysc(fabsf((float)t - 7.5f) * 0.25f);
        z += w;
        acc += w * s[i];
    }
    dst[idx] = acc / z;
}

// ---------------- K4: raw channels downsample along H ----------------------
__global__ void k_raw_downH(const float* __restrict__ pred, const float* __restrict__ I,
                            float* __restrict__ RH) {
    int idx = blockIdx.x * 256 + threadIdx.x;
    const int total = NIMG * 3 * DH * FW;
    if (idx >= total) return;
    int x  = idx % FW;
    int t1 = idx / FW;
    int yo = t1 % DH;
    int t2 = t1 / DH;
    int c  = t2 % 3;
    int img = t2 / 3;
    const float* src;
    if (img < 2) {
        src = pred + (img * 3 + c) * FH * FW;
    } else {
        int j = (img - 2) >> 1, b = (img - 2) & 1;
        src = I + (((b * 2 + j) * 3) + c) * FH * FW;
    }
    float acc = 0.f, z = 0.f;
#pragma unroll
    for (int t = 0; t < 16; ++t) {
        int r = 4 * yo - 6 + t;
        if (r < 0 || r >= FH) continue;
        float w = keysc(fabsf((float)t - 7.5f) * 0.25f);
        z += w;
        acc += w * src[r * FW + x];
    }
    RH[idx] = acc / z;
}

// ---------------- K5: n2 per (neighbor image, position) --------------------
__global__ void k_n2(const float* __restrict__ CD, float* __restrict__ N2) {
    int idx = blockIdx.x * 256 + threadIdx.x;
    if (idx >= 4 * PLANE) return;
    int img4 = idx / PLANE;
    int pos  = idx % PLANE;
    int y = pos / DW, x = pos % DW;
    int ry[3], rx[3];
#pragma unroll
    for (int kk = 0; kk < 3; ++kk) {
        ry[kk] = refl(y + kk - 1, DH);
        rx[kk] = refl(x + kk - 1, DW);
    }
    const float* C = CD + (2 + img4) * 9 * PLANE;
    float s = 0.f;
#pragma unroll
    for (int c = 0; c < 9; ++c)
#pragma unroll
        for (int ky = 0; ky < 3; ++ky)
#pragma unroll
            for (int kx = 0; kx < 3; ++kx) {
                float v = C[c * PLANE + ry[ky] * DW + rx[kx]];
                s += v * v;
            }
    N2[idx] = s;
}

// ---------------- K6: matching via LDS-staged windows ----------------------
// block = 32 px of one row (y) x 8 candidate groups; grid = 2b * 96 rows * 3 xtiles
// center patch hoisted to registers: candidate loop reads nb-LDS only.
__global__ __launch_bounds__(256, 1) void k_match(const float* __restrict__ CD,
                                                  const float* __restrict__ N2,
                                                  const float* __restrict__ RD,
                                                  float* __restrict__ partial) {
    __shared__ float nb[2][9][9][40];   // [j][c][row y-4+u][col x0-4+v]
    __shared__ float ct[9][3][34];      // [c][row y-1+u][col x0-1+v]
    __shared__ float sbd[256];
    __shared__ int   sbn[256];
    __shared__ float red[32];

    int bid = blockIdx.x;          // b*288 + y*3 + xt
    int b   = bid / 288;
    int rem = bid % 288;
    int y   = rem / 3;
    int x0  = (rem % 3) * 32;

    int px = threadIdx.x & 31;
    int g  = threadIdx.x >> 5;     // candidate group 0..7
    int x  = x0 + px;

    // ---- stage neighbor windows (clamped absolute coords; unused slots never read)
    for (int idx = threadIdx.x; idx < 2 * 9 * 9 * 40; idx += 256) {
        int j   = idx / 3240;
        int r1  = idx % 3240;
        int c   = r1 / 360;
        int r2  = r1 % 360;
        int u   = r2 / 40;
        int v   = r2 % 40;
        int gy  = clampi(y - 4 + u);
        int gx  = clampi(x0 - 4 + v);
        nb[j][c][u][v] = CD[((2 + 2 * j + b) * 9 + c) * PLANE + gy * DW + gx];
    }
    // ---- stage center window
    for (int idx = threadIdx.x; idx < 9 * 3 * 34; idx += 256) {
        int c = idx / 102;
        int r1 = idx % 102;
        int u = r1 / 34;
        int v = r1 % 34;
        int gy = clampi(y - 1 + u);
        int gx = clampi(x0 - 1 + v);
        ct[c][u][v] = CD[(b * 9 + c) * PLANE + gy * DW + gx];
    }
    __syncthreads();

    // center patch -> registers (static indices only; read once, reused 13x)
    int cy_s[3], cx_s[3];
#pragma unroll
    for (int kk = 0; kk < 3; ++kk) {
        cy_s[kk] = refl(y + kk - 1, DH) - (y - 1);
        cx_s[kk] = refl(x + kk - 1, DW) - (x0 - 1);
    }
    float p[81];
#pragma unroll
    for (int c = 0; c < 9; ++c)
#pragma unroll
        for (int ky = 0; ky < 3; ++ky)
#pragma unroll
            for (int kx = 0; kx < 3; ++kx)
                p[c * 9 + ky * 3 + kx] = ct[c][cy_s[ky]][cx_s[kx]];

    float best = INFINITY;
    int bn = 1 << 30;
    for (int k = 0; k < 13; ++k) {
        int n = 8 * k + g;
        if (n >= 98) break;
        int j = n / 49, rr = n % 49;
        int dy = rr / 7 - 3, dx = rr % 7 - 3;
        int yy = refl(y + dy, DH), xx = refl(x + dx, DW);   // first reflect
        int ry_s[3], rx_s[3];
#pragma unroll
        for (int kk = 0; kk < 3; ++kk) {                    // second reflect -> slots
            ry_s[kk] = refl(yy + kk - 1, DH) - (y - 4);
            rx_s[kk] = refl(xx + kk - 1, DW) - (x0 - 4);
        }
        float dot = 0.f;
#pragma unroll
        for (int c = 0; c < 9; ++c)
#pragma unroll
            for (int ky = 0; ky < 3; ++ky)
#pragma unroll
                for (int kx = 0; kx < 3; ++kx)
                    dot += p[c * 9 + ky * 3 + kx] * nb[j][c][ry_s[ky]][rx_s[kx]];
        float dis = N2[(2 * j + b) * PLANE + yy * DW + xx] - 2.f * dot;
        if (dis < best) { best = dis; bn = n; }   // n ascending within group
    }
    sbd[threadIdx.x] = best;
    sbn[threadIdx.x] = bn;
    __syncthreads();

    // ---- per-pixel lex-min across the 8 groups + loss gather (g==0 threads)
    if (g == 0) {
        float d0 = sbd[px];
        int   n0 = sbn[px];
#pragma unroll
        for (int gg = 1; gg < 8; ++gg) {
            float d = sbd[gg * 32 + px];
            int   n = sbn[gg * 32 + px];
            if (d < d0 || (d == d0 && n < n0)) { d0 = d; n0 = n; }
        }
        int j = n0 / 49, rr = n0 % 49;
        int dy = rr / 7 - 3, dx = rr % 7 - 3;
        int yy = refl(y + dy, DH), xx = refl(x + dx, DW);
        int ry0[3], rx0[3], ry[3], rx[3];
#pragma unroll
        for (int kk = 0; kk < 3; ++kk) {
            ry0[kk] = refl(y + kk - 1, DH);
            rx0[kk] = refl(x + kk - 1, DW);
            ry[kk]  = refl(yy + kk - 1, DH);
            rx[kk]  = refl(xx + kk - 1, DW);
        }
        const float* RDp = RD + b * 3 * PLANE;
        const float* RDn = RD + (2 + 2 * j + b) * 3 * PLANE;
        float loss = 0.f;
#pragma unroll
        for (int c = 0; c < 3; ++c)
#pragma unroll
            for (int ky = 0; ky < 3; ++ky)
#pragma unroll
                for (int kx = 0; kx < 3; ++kx) {
                    float a = RDp[c * PLANE + ry0[ky] * DW + rx0[kx]];
                    float m = RDn[c * PLANE + ry[ky] * DW + rx[kx]];
                    float d = a - m;
                    loss += d * d;
                }
        red[px] = loss;
    }
    __syncthreads();
    if (threadIdx.x == 0) {
        float s = 0.f;
#pragma unroll
        for (int i = 0; i < 32; ++i) s += red[i];
        partial[bid] = s;
    }
}

// ---------------- K8: final reduction --------------------------------------
#define NPART 576
__global__ void k_final(const float* __restrict__ partial, float* __restrict__ out) {
    __shared__ float red[256];
    float v = 0.f;
    for (int i = threadIdx.x; i < NPART; i += 256) v += partial[i];
    red[threadIdx.x] = v;
    __syncthreads();
#pragma unroll
    for (int s = 128; s > 0; s >>= 1) {
        if (threadIdx.x < s) red[threadIdx.x] += red[threadIdx.x + s];
        __syncthreads();
    }
    // mean over [b=2, hw=9216, 27] with the 0.5 factor
    if (threadIdx.x == 0) out[0] = red[0] * (0.5f / 497664.0f);
}

extern "C" void kernel_launch(void* const* d_in, const int* in_sizes, int n_in,
                              void* d_out, int out_size, void* d_ws, size_t ws_size,
                              hipStream_t stream) {
    const float* pred = (const float*)d_in[0];   // [2,3,384,384]
    const float* I    = (const float*)d_in[1];   // [2,2,3,384,384]
    float* out = (float*)d_out;
    float* ws  = (float*)d_ws;

    // workspace layout (floats):
    //   CD   [0, 497664)                       6*9*96*96
    //   RD   [497664, 663552)                  6*3*96*96
    //   scratch S = 663552:
    //     gray [S, S+884736)         (dead after census_downH)
    //     CH   [S+884736, S+2875392) (dead after downW)
    //     RH   [S+2875392, S+3538944)(dead after downW)
    //   reused after downW:
    //     N2   [S, S+36864)
    //     part [S+36864, S+37440)
    float* CD   = ws;
    float* RD   = CD + 497664;
    float* S    = RD + 165888;
    float* gray = S;
    float* CH   = S + 884736;
    float* RH   = CH + 1990656;
    float* N2   = S;
    float* part = S + 36864;

    k_gray<<<(NIMG * FH * FW + 255) / 256, 256, 0, stream>>>(pred, I, gray);
    k_census_downH<<<(NIMG * DH * FW + 255) / 256, 256, 0, stream>>>(gray, CH);
    k_raw_downH<<<(NIMG * 3 * DH * FW + 255) / 256, 256, 0, stream>>>(pred, I, RH);
    k_downW<<<((NIMG * 12 * DH) * DW + 255) / 256, 256, 0, stream>>>(CH, CD, NIMG * 12 * DH);
    k_n2<<<(4 * PLANE + 255) / 256, 256, 0, stream>>>(CD, N2);
    k_match<<<576, 256, 0, stream>>>(CD, N2, RD, part);
    k_final<<<1, 256, 0, stream>>>(part, out);
}